// Round 1
// baseline (1288.411 us; speedup 1.0000x reference)
//
#include <hip/hip_runtime.h>
#include <math.h>

// Problem constants (shapes fixed by setup_inputs)
#define CC     256      // hidden dim
#define NH     8        // heads
#define HD     32       // head dim
#define BT     16       // batch*frames
#define TQ     32       // query tile per block
#define AS     258      // LDS A stride (floats): even (float2-aligned) + conflict-break
#define LM     70       // memory length (30 text + 40 amr)
#define LT     30
#define LA     40

// ---------------- prep 1: K,V rows per batch b (140 rows) ----------------
__global__ __launch_bounds__(256) void prep_kv(
    const float* __restrict__ text_feats,  // [2,30,256]
    const float* __restrict__ amr_feats,   // [2,40,256]
    const int*   __restrict__ text_pad,    // [2,30]
    const int*   __restrict__ amr_pad,     // [2,40]
    const float* __restrict__ in_w,        // [768,256]
    const float* __restrict__ in_b,        // [768]
    float* __restrict__ Kout,              // [2,70,256]
    float* __restrict__ Vout) {            // [2,70,256]
  int blk = blockIdx.x;          // 0..139
  int b = blk / LM;
  int l = blk - b * LM;
  int t = threadIdx.x;           // 0..255 = output channel
  __shared__ float mem[CC], kin[CC];
  __shared__ float shx[2];
  if (t == 0 && l < LT) {
    float cum = 0.f, cl = 0.f;
    for (int j = 0; j < LT; ++j) {
      float nm = text_pad[b * LT + j] ? 0.f : 1.f;
      cum += nm;
      if (j == l) cl = cum;
    }
    shx[0] = cl;       // x_embed[l]
    shx[1] = cum;      // x_embed[last]
  }
  __syncthreads();
  float m;
  if (l < LT) m = text_feats[(b * LT + l) * CC + t];
  else        m = amr_feats[(b * LA + (l - LT)) * CC + t];
  float pos = 0.f;
  if (l < LT) {
    float xh = shx[0] / (shx[1] + 1e-6f) * 6.283185307179586f;
    float i2 = (float)((t >> 1) * 2);
    float dt = powf(10000.0f, i2 / 256.0f);
    float val = xh / dt;
    pos = (t & 1) ? cosf(val) : sinf(val);
  }
  mem[t] = m;
  kin[t] = m + pos;
  __syncthreads();
  const float4* wk4 = (const float4*)(in_w + (size_t)(CC + t) * CC);
  const float4* wv4 = (const float4*)(in_w + (size_t)(2 * CC + t) * CC);
  float ak = in_b[CC + t];
  float av = in_b[2 * CC + t];
  #pragma unroll 4
  for (int c4 = 0; c4 < 64; ++c4) {
    float4 wk = wk4[c4], wv = wv4[c4];
    int c = c4 * 4;
    ak += kin[c] * wk.x + kin[c + 1] * wk.y + kin[c + 2] * wk.z + kin[c + 3] * wk.w;
    av += mem[c] * wv.x + mem[c + 1] * wv.y + mem[c + 2] * wv.z + mem[c + 3] * wv.w;
  }
  Kout[(size_t)(b * LM + l) * CC + t] = ak;
  Vout[(size_t)(b * LM + l) * CC + t] = av;
}

// ------- prep 2: transpose+pair Wq and Wo for coalesced reads; valid-key list -------
__global__ __launch_bounds__(256) void prep_wt(
    const float* __restrict__ in_w,   // rows 0..255 = Wq
    const float* __restrict__ out_w,  // [256,256] Wo
    float2* __restrict__ wqt2,        // [128][256]: {Wq[co][2c2], Wq[co][2c2+1]}
    float2* __restrict__ wot2,
    const int* __restrict__ tp, const int* __restrict__ ap,
    int* __restrict__ vidx) {         // [2][80]: indices, count at [79]
  int idx = blockIdx.x * 256 + threadIdx.x;   // 0..65535
  int c2 = (idx >> 8) & 127;
  int co = idx & 255;
  if (idx < 32768)
    wqt2[idx] = make_float2(in_w[co * CC + 2 * c2], in_w[co * CC + 2 * c2 + 1]);
  else
    wot2[idx - 32768] = make_float2(out_w[co * CC + 2 * c2], out_w[co * CC + 2 * c2 + 1]);
  if (blockIdx.x == 0 && threadIdx.x < 2) {
    int b = threadIdx.x, n = 0;
    for (int k = 0; k < LM; ++k) {
      int pad = (k < LT) ? tp[b * LT + k] : ap[b * LA + (k - LT)];
      if (!pad) vidx[b * 80 + n++] = k;
    }
    vidx[b * 80 + 79] = n;
  }
}

// ---------------- main fused kernel: one block = 32 query positions ----------------
__global__ __launch_bounds__(256) void attn_main(
    const float* __restrict__ f0, const float* __restrict__ p0,
    const float* __restrict__ f1, const float* __restrict__ p1,
    const float* __restrict__ f2, const float* __restrict__ p2,
    const float* __restrict__ f3, const float* __restrict__ p3,
    const float* __restrict__ Kws, const float* __restrict__ Vws,
    const float2* __restrict__ wqt2, const float2* __restrict__ wot2,
    const float* __restrict__ in_b, const float* __restrict__ out_b,
    const int* __restrict__ vidx, float* __restrict__ out) {
  __shared__ float A[TQ * AS];   // reused: qin[qi][c] -> Q[c][qi] (swizzled) -> ao[qi][c]
  int t = threadIdx.x;
  int blk = blockIdx.x;
  int bt = blk / 267;
  int r = blk - bt * 267;
  const float* xb; const float* pb; float* ob; int HW; int tile;
  if (r < 200)      { HW = 6400; xb = f0; pb = p0; ob = out;            tile = r; }
  else if (r < 250) { HW = 1600; xb = f1; pb = p1; ob = out + 26214400; tile = r - 200; }
  else if (r < 263) { HW = 400;  xb = f2; pb = p2; ob = out + 32768000; tile = r - 250; }
  else              { HW = 100;  xb = f3; pb = p3; ob = out + 34406400; tile = r - 263; }
  size_t base = (size_t)bt * CC * HW;
  xb += base; pb += base; ob += base;
  int q0 = tile * TQ;
  int b = bt >> 3;   // bt // T, T=8

  // ---- Phase 1: qin = x + p -> A[qi][c]
  {
    int c0 = t >> 3;               // 0..31
    int qi0 = (t & 7) * 4;         // float4 chunk of the 32 queries
    int pos = q0 + qi0;
    bool ok = pos < HW;            // HW % 4 == 0 -> whole float4 in/out of range
    #pragma unroll
    for (int it = 0; it < 8; ++it) {
      int c = it * 32 + c0;
      float4 xv = make_float4(0.f, 0.f, 0.f, 0.f), pv = xv;
      if (ok) {
        xv = *(const float4*)(xb + (size_t)c * HW + pos);
        pv = *(const float4*)(pb + (size_t)c * HW + pos);
      }
      A[(qi0 + 0) * AS + c] = xv.x + pv.x;
      A[(qi0 + 1) * AS + c] = xv.y + pv.y;
      A[(qi0 + 2) * AS + c] = xv.z + pv.z;
      A[(qi0 + 3) * AS + c] = xv.w + pv.w;
    }
  }
  __syncthreads();

  // ---- Phase 2: Q^T = Wq * qin + bq -> A[c][qi] (swizzled)
  {
    int co = t & 127;
    int qbase = (t >> 7) * 16;
    float acc0[16], acc1[16];
    #pragma unroll
    for (int q = 0; q < 16; ++q) { acc0[q] = 0.f; acc1[q] = 0.f; }
    for (int c2 = 0; c2 < 128; ++c2) {
      float2 w0 = wqt2[c2 * 256 + co];
      float2 w1 = wqt2[c2 * 256 + co + 128];
      #pragma unroll
      for (int q = 0; q < 16; ++q) {
        float2 a = *(const float2*)&A[(qbase + q) * AS + 2 * c2];
        acc0[q] += a.x * w0.x + a.y * w0.y;
        acc1[q] += a.x * w1.x + a.y * w1.y;
      }
    }
    float bq0 = in_b[co], bq1 = in_b[co + 128];
    __syncthreads();   // all reads of qin done before overwrite
    #pragma unroll
    for (int q = 0; q < 16; ++q) {
      int qi = qbase + q;
      A[co * 32 + ((qi + co) & 31)] = acc0[q] + bq0;
      A[(co + 128) * 32 + ((qi + co) & 31)] = acc1[q] + bq1;
    }
  }
  __syncthreads();

  // ---- Phase 3/4: per-(head, query) online-softmax attention; K,V from L2
  {
    int qi = t & 31;
    int h = t >> 5;
    float qreg[HD];
    #pragma unroll
    for (int d = 0; d < HD; ++d) {
      int c = h * HD + d;
      qreg[d] = A[c * 32 + ((qi + c) & 31)];
    }
    __syncthreads();   // all Q fragment loads done before ao overwrites A
    const int* vb = vidx + b * 80;
    int nv = vb[79];
    const float* Kb = Kws + (size_t)(b * LM) * CC + h * HD;
    const float* Vb = Vws + (size_t)(b * LM) * CC + h * HD;
    float m = -1e30f, sum = 0.f;
    float oacc[HD];
    #pragma unroll
    for (int d = 0; d < HD; ++d) oacc[d] = 0.f;
    for (int i = 0; i < nv; ++i) {
      int k = vb[i];
      const float4* kp = (const float4*)(Kb + (size_t)k * CC);
      float s = 0.f;
      #pragma unroll
      for (int d4 = 0; d4 < 8; ++d4) {
        float4 kv = kp[d4];
        s += qreg[4*d4+0]*kv.x + qreg[4*d4+1]*kv.y + qreg[4*d4+2]*kv.z + qreg[4*d4+3]*kv.w;
      }
      s *= 0.17677669529663687f;   // 1/sqrt(32)
      float mn = fmaxf(m, s);
      float al = __expf(m - mn);
      float pw = __expf(s - mn);
      sum = sum * al + pw;
      const float4* vp = (const float4*)(Vb + (size_t)k * CC);
      #pragma unroll
      for (int d4 = 0; d4 < 8; ++d4) {
        float4 vv = vp[d4];
        oacc[4*d4+0] = oacc[4*d4+0]*al + pw*vv.x;
        oacc[4*d4+1] = oacc[4*d4+1]*al + pw*vv.y;
        oacc[4*d4+2] = oacc[4*d4+2]*al + pw*vv.z;
        oacc[4*d4+3] = oacc[4*d4+3]*al + pw*vv.w;
      }
      m = mn;
    }
    float inv = 1.f / sum;
    #pragma unroll
    for (int d = 0; d < HD; ++d)
      A[qi * AS + h * HD + d] = oacc[d] * inv;   // ao[qi][c]
  }
  __syncthreads();

  // ---- Phase 5: tgt2 = Wo * ao + bo; gated = x * tgt2; store [C,HW] layout
  {
    int co = t & 127;
    int qbase = (t >> 7) * 16;
    float acc0[16], acc1[16];
    #pragma unroll
    for (int q = 0; q < 16; ++q) { acc0[q] = 0.f; acc1[q] = 0.f; }
    for (int c2 = 0; c2 < 128; ++c2) {
      float2 w0 = wot2[c2 * 256 + co];
      float2 w1 = wot2[c2 * 256 + co + 128];
      #pragma unroll
      for (int q = 0; q < 16; ++q) {
        float2 a = *(const float2*)&A[(qbase + q) * AS + 2 * c2];
        acc0[q] += a.x * w0.x + a.y * w0.y;
        acc1[q] += a.x * w1.x + a.y * w1.y;
      }
    }
    float bo0 = out_b[co], bo1 = out_b[co + 128];
    #pragma unroll
    for (int j = 0; j < 4; ++j) {
      int pos = q0 + qbase + 4 * j;
      if (pos < HW) {
        float4 x0 = *(const float4*)(xb + (size_t)co * HW + pos);
        float4 g0 = make_float4((acc0[4*j+0] + bo0) * x0.x, (acc0[4*j+1] + bo0) * x0.y,
                                (acc0[4*j+2] + bo0) * x0.z, (acc0[4*j+3] + bo0) * x0.w);
        *(float4*)(ob + (size_t)co * HW + pos) = g0;
        float4 x1 = *(const float4*)(xb + (size_t)(co + 128) * HW + pos);
        float4 g1 = make_float4((acc1[4*j+0] + bo1) * x1.x, (acc1[4*j+1] + bo1) * x1.y,
                                (acc1[4*j+2] + bo1) * x1.z, (acc1[4*j+3] + bo1) * x1.w);
        *(float4*)(ob + (size_t)(co + 128) * HW + pos) = g1;
      }
    }
  }
}

extern "C" void kernel_launch(void* const* d_in, const int* in_sizes, int n_in,
                              void* d_out, int out_size, void* d_ws, size_t ws_size,
                              hipStream_t stream) {
  // setup_inputs() order:
  const float* f0 = (const float*)d_in[0];
  const float* p0 = (const float*)d_in[1];
  const float* f1 = (const float*)d_in[2];
  const float* p1 = (const float*)d_in[3];
  const float* f2 = (const float*)d_in[4];
  const float* p2 = (const float*)d_in[5];
  const float* f3 = (const float*)d_in[6];
  const float* p3 = (const float*)d_in[7];
  const float* text_feats = (const float*)d_in[8];
  const float* amr_feats  = (const float*)d_in[9];
  const int*   text_pad   = (const int*)d_in[10];
  const int*   amr_pad    = (const int*)d_in[11];
  const float* in_w  = (const float*)d_in[12];
  const float* in_b  = (const float*)d_in[13];
  const float* out_w = (const float*)d_in[14];
  const float* out_b = (const float*)d_in[15];
  float* out = (float*)d_out;

  // workspace layout (floats)
  float* ws   = (float*)d_ws;
  float* Kws  = ws;               // 2*70*256 = 35840
  float* Vws  = ws + 35840;       // 35840
  float* wqt  = ws + 71680;       // 65536 (as float2[32768])
  float* wot  = ws + 137216;      // 65536
  int*   vidx = (int*)(ws + 202752);  // 160 ints

  prep_kv<<<2 * LM, 256, 0, stream>>>(text_feats, amr_feats, text_pad, amr_pad,
                                      in_w, in_b, Kws, Vws);
  prep_wt<<<256, 256, 0, stream>>>(in_w, out_w, (float2*)wqt, (float2*)wot,
                                   text_pad, amr_pad, vidx);
  attn_main<<<BT * 267, 256, 0, stream>>>(f0, p0, f1, p1, f2, p2, f3, p3,
                                          Kws, Vws, (const float2*)wqt, (const float2*)wot,
                                          in_b, out_b, vidx, out);
}

// Round 2
// 866.244 us; speedup vs baseline: 1.4874x; 1.4874x over previous
//
#include <hip/hip_runtime.h>
#include <math.h>

#define CC 256
#define NH 8
#define HD 32
#define BT 16
#define TQ 32
#define LM 70
#define LT 30
#define LA 40
#define ABS 264   // Abuf row stride in bf16 elems (528B = 33*16B -> aligned, conflict-spread)

typedef __bf16 bf16x8 __attribute__((ext_vector_type(8)));
typedef float floatx4 __attribute__((ext_vector_type(4)));
typedef unsigned short ushortx8 __attribute__((ext_vector_type(8)));

__device__ inline unsigned short f2bf(float f) {
  unsigned int u = __float_as_uint(f);
  u += 0x7fffu + ((u >> 16) & 1u);   // RNE
  return (unsigned short)(u >> 16);
}

// ---------------- prep 1: K,V rows per batch b (140 rows), fp32 ----------------
__global__ __launch_bounds__(256) void prep_kv(
    const float* __restrict__ text_feats,  // [2,30,256]
    const float* __restrict__ amr_feats,   // [2,40,256]
    const int*   __restrict__ text_pad,    // [2,30]
    const float* __restrict__ in_w,        // [768,256]
    const float* __restrict__ in_b,        // [768]
    float* __restrict__ Kout,              // [2,70,256]
    float* __restrict__ Vout) {            // [2,70,256]
  int blk = blockIdx.x;          // 0..139
  int b = blk / LM;
  int l = blk - b * LM;
  int t = threadIdx.x;           // output channel
  __shared__ float mem[CC], kin[CC];
  __shared__ float shx[2];
  if (t == 0 && l < LT) {
    float cum = 0.f, cl = 0.f;
    for (int j = 0; j < LT; ++j) {
      float nm = text_pad[b * LT + j] ? 0.f : 1.f;
      cum += nm;
      if (j == l) cl = cum;
    }
    shx[0] = cl;
    shx[1] = cum;
  }
  __syncthreads();
  float m;
  if (l < LT) m = text_feats[(b * LT + l) * CC + t];
  else        m = amr_feats[(b * LA + (l - LT)) * CC + t];
  float pos = 0.f;
  if (l < LT) {
    float xh = shx[0] / (shx[1] + 1e-6f) * 6.283185307179586f;
    float i2 = (float)((t >> 1) * 2);
    float dt = powf(10000.0f, i2 / 256.0f);
    float val = xh / dt;
    pos = (t & 1) ? cosf(val) : sinf(val);
  }
  mem[t] = m;
  kin[t] = m + pos;
  __syncthreads();
  const float4* wk4 = (const float4*)(in_w + (size_t)(CC + t) * CC);
  const float4* wv4 = (const float4*)(in_w + (size_t)(2 * CC + t) * CC);
  float ak = in_b[CC + t];
  float av = in_b[2 * CC + t];
  #pragma unroll 4
  for (int c4 = 0; c4 < 64; ++c4) {
    float4 wk = wk4[c4], wv = wv4[c4];
    int c = c4 * 4;
    ak += kin[c] * wk.x + kin[c + 1] * wk.y + kin[c + 2] * wk.z + kin[c + 3] * wk.w;
    av += mem[c] * wv.x + mem[c + 1] * wv.y + mem[c + 2] * wv.z + mem[c + 3] * wv.w;
  }
  Kout[(size_t)(b * LM + l) * CC + t] = ak;
  Vout[(size_t)(b * LM + l) * CC + t] = av;
}

// ---- prep 2: pack Wq,Wo into bf16 MFMA B-fragment layout + valid-key list ----
// B-frag slot r = (nt*8 + ks)*64 + lane holds W[nt*16+(lane&15)][ks*32+(lane>>4)*8 + j]
__global__ __launch_bounds__(256) void prep_pack(
    const float* __restrict__ in_w,   // rows 0..255 = Wq
    const float* __restrict__ out_w,  // [256,256] Wo
    unsigned short* __restrict__ wq_pack,
    unsigned short* __restrict__ wo_pack,
    const int* __restrict__ tp, const int* __restrict__ ap,
    int* __restrict__ vidx) {         // [2][80]: indices, count at [79]
  int idx = blockIdx.x * 256 + threadIdx.x;   // 0..16383
  int m = idx >> 13;
  int r = idx & 8191;
  int lane = r & 63;
  int ks = (r >> 6) & 7;
  int nt = (r >> 9) & 15;
  int row = nt * 16 + (lane & 15);
  int k0 = ks * 32 + (lane >> 4) * 8;
  const float* W = m ? out_w : in_w;
  unsigned short* dst = (m ? wo_pack : wq_pack) + (size_t)r * 8;
  #pragma unroll
  for (int j = 0; j < 8; ++j) dst[j] = f2bf(W[row * CC + k0 + j]);
  if (blockIdx.x == 0 && threadIdx.x < 2) {
    int b = threadIdx.x, n = 0;
    for (int k = 0; k < LM; ++k) {
      int pad = (k < LT) ? tp[b * LT + k] : ap[b * LA + (k - LT)];
      if (!pad) vidx[b * 80 + n++] = k;
    }
    vidx[b * 80 + 79] = n;
  }
}

// GEMM: D[q 0..31][c 0..255] = A[32x256] * W^T via 16x16x32 bf16 MFMA
// wave w covers channels 64w..64w+63 (4 ntiles), 2 mtiles, 8 k-steps
__device__ inline void mfma_gemm(const unsigned short* __restrict__ Wp,
                                 const unsigned short* Abuf_s,
                                 int w, int lane, floatx4 acc[2][4]) {
  int arow = lane & 15;
  int aq = (lane >> 4) * 8;
  #pragma unroll
  for (int ks = 0; ks < 8; ++ks) {
    bf16x8 a0 = *(const bf16x8*)&Abuf_s[arow * ABS + ks * 32 + aq];
    bf16x8 a1 = *(const bf16x8*)&Abuf_s[(arow + 16) * ABS + ks * 32 + aq];
    #pragma unroll
    for (int ntl = 0; ntl < 4; ++ntl) {
      bf16x8 b = *(const bf16x8*)(Wp + ((size_t)((w * 4 + ntl) * 8 + ks) * 64 + lane) * 8);
      acc[0][ntl] = __builtin_amdgcn_mfma_f32_16x16x32_bf16(a0, b, acc[0][ntl], 0, 0, 0);
      acc[1][ntl] = __builtin_amdgcn_mfma_f32_16x16x32_bf16(a1, b, acc[1][ntl], 0, 0, 0);
    }
  }
}

// scatter D-frags (+bias) into swizzled fp32 [c][qi] buffer: addr = c*32 + ((qi+c)&31)
__device__ inline void store_cols(float* Qb, const float* __restrict__ bias,
                                  int w, int lane, floatx4 acc[2][4]) {
  #pragma unroll
  for (int ntl = 0; ntl < 4; ++ntl) {
    int c = w * 64 + ntl * 16 + (lane & 15);
    float bv = bias[c];
    #pragma unroll
    for (int mt = 0; mt < 2; ++mt) {
      #pragma unroll
      for (int reg = 0; reg < 4; ++reg) {
        int qi = mt * 16 + ((lane >> 4) & 3) * 4 + reg;
        Qb[c * 32 + ((qi + c) & 31)] = acc[mt][ntl][reg] + bv;
      }
    }
  }
}

// ---------------- main fused kernel: one block = 32 query positions ----------------
__global__ __launch_bounds__(256) void attn_main(
    const float* __restrict__ f0, const float* __restrict__ p0,
    const float* __restrict__ f1, const float* __restrict__ p1,
    const float* __restrict__ f2, const float* __restrict__ p2,
    const float* __restrict__ f3, const float* __restrict__ p3,
    const float* __restrict__ Kws, const float* __restrict__ Vws,
    const unsigned short* __restrict__ wq_pack,
    const unsigned short* __restrict__ wo_pack,
    const float* __restrict__ in_b, const float* __restrict__ out_b,
    const int* __restrict__ vidx, float* __restrict__ out) {
  __shared__ unsigned short Abuf[TQ * ABS];  // bf16 A-operand tile (qin -> ao)
  __shared__ float Qbuf[TQ * CC];            // fp32 swizzled [c][qi] (Q -> tgt2)
  int t = threadIdx.x;
  int lane = t & 63;
  int w = t >> 6;
  int blk = blockIdx.x;
  int bt = blk / 267;
  int r = blk - bt * 267;
  const float* xb; const float* pb; float* ob; int HW; int tile;
  if (r < 200)      { HW = 6400; xb = f0; pb = p0; ob = out;            tile = r; }
  else if (r < 250) { HW = 1600; xb = f1; pb = p1; ob = out + 26214400; tile = r - 200; }
  else if (r < 263) { HW = 400;  xb = f2; pb = p2; ob = out + 32768000; tile = r - 250; }
  else              { HW = 100;  xb = f3; pb = p3; ob = out + 34406400; tile = r - 263; }
  size_t base = (size_t)bt * CC * HW;
  xb += base; pb += base; ob += base;
  int q0 = tile * TQ;
  int b = bt >> 3;

  int c0 = t >> 3;
  int qi0 = (t & 7) * 4;

  // ---- P1: qin = x + p -> Abuf bf16 [qi][c]
  {
    int pos = q0 + qi0;
    bool ok = pos < HW;
    #pragma unroll
    for (int it = 0; it < 8; ++it) {
      int c = it * 32 + c0;
      float4 xv = make_float4(0.f, 0.f, 0.f, 0.f), pv = xv;
      if (ok) {
        xv = *(const float4*)(xb + (size_t)c * HW + pos);
        pv = *(const float4*)(pb + (size_t)c * HW + pos);
      }
      Abuf[(qi0 + 0) * ABS + c] = f2bf(xv.x + pv.x);
      Abuf[(qi0 + 1) * ABS + c] = f2bf(xv.y + pv.y);
      Abuf[(qi0 + 2) * ABS + c] = f2bf(xv.z + pv.z);
      Abuf[(qi0 + 3) * ABS + c] = f2bf(xv.w + pv.w);
    }
  }
  __syncthreads();

  // ---- P2: Q = qin @ Wq^T + bq  (MFMA) -> Qbuf
  {
    floatx4 acc[2][4];
    #pragma unroll
    for (int i = 0; i < 2; ++i)
      #pragma unroll
      for (int j = 0; j < 4; ++j) acc[i][j] = (floatx4){0.f, 0.f, 0.f, 0.f};
    mfma_gemm(wq_pack, Abuf, w, lane, acc);
    store_cols(Qbuf, in_b, w, lane, acc);   // Qbuf untouched before: no sync needed
  }
  __syncthreads();

  // ---- P3: per-(head,query) online-softmax attention; write ao -> Abuf bf16
  {
    int qi = t & 31;
    int h = t >> 5;
    float qreg[HD];
    #pragma unroll
    for (int d = 0; d < HD; ++d) {
      int c = h * HD + d;
      qreg[d] = Qbuf[c * 32 + ((qi + c) & 31)];
    }
    const int* vb = vidx + b * 80;
    int nv = vb[79];
    const float* Kb = Kws + (size_t)(b * LM) * CC + h * HD;
    const float* Vb = Vws + (size_t)(b * LM) * CC + h * HD;
    float m = -1e30f, sum = 0.f;
    float oacc[HD];
    #pragma unroll
    for (int d = 0; d < HD; ++d) oacc[d] = 0.f;
    for (int i = 0; i < nv; ++i) {
      int k = vb[i];
      const float4* kp = (const float4*)(Kb + (size_t)k * CC);
      float s = 0.f;
      #pragma unroll
      for (int d4 = 0; d4 < 8; ++d4) {
        float4 kv = kp[d4];
        s += qreg[4*d4+0]*kv.x + qreg[4*d4+1]*kv.y + qreg[4*d4+2]*kv.z + qreg[4*d4+3]*kv.w;
      }
      s *= 0.17677669529663687f;
      float mn = fmaxf(m, s);
      float al = __expf(m - mn);
      float pw = __expf(s - mn);
      sum = sum * al + pw;
      const float4* vp = (const float4*)(Vb + (size_t)k * CC);
      #pragma unroll
      for (int d4 = 0; d4 < 8; ++d4) {
        float4 vv = vp[d4];
        oacc[4*d4+0] = oacc[4*d4+0]*al + pw*vv.x;
        oacc[4*d4+1] = oacc[4*d4+1]*al + pw*vv.y;
        oacc[4*d4+2] = oacc[4*d4+2]*al + pw*vv.z;
        oacc[4*d4+3] = oacc[4*d4+3]*al + pw*vv.w;
      }
      m = mn;
    }
    float inv = 1.f / sum;
    #pragma unroll
    for (int j = 0; j < 4; ++j) {
      ushortx8 pk;
      #pragma unroll
      for (int e = 0; e < 8; ++e) pk[e] = f2bf(oacc[j * 8 + e] * inv);
      *(ushortx8*)&Abuf[qi * ABS + h * HD + j * 8] = pk;
    }
  }
  __syncthreads();

  // ---- P4: tgt2 = ao @ Wo^T + bo (MFMA) -> Qbuf
  {
    floatx4 acc[2][4];
    #pragma unroll
    for (int i = 0; i < 2; ++i)
      #pragma unroll
      for (int j = 0; j < 4; ++j) acc[i][j] = (floatx4){0.f, 0.f, 0.f, 0.f};
    mfma_gemm(wo_pack, Abuf, w, lane, acc);
    store_cols(Qbuf, out_b, w, lane, acc);  // Qbuf(Q) reads all done at P3-end sync
  }
  __syncthreads();

  // ---- P5: gated = x * tgt2; coalesced store in [C,HW] layout
  {
    int pos = q0 + qi0;
    if (pos < HW) {
      #pragma unroll
      for (int it = 0; it < 8; ++it) {
        int c = it * 32 + c0;
        float4 xv = *(const float4*)(xb + (size_t)c * HW + pos);
        float4 g;
        g.x = xv.x * Qbuf[c * 32 + ((qi0 + 0 + c) & 31)];
        g.y = xv.y * Qbuf[c * 32 + ((qi0 + 1 + c) & 31)];
        g.z = xv.z * Qbuf[c * 32 + ((qi0 + 2 + c) & 31)];
        g.w = xv.w * Qbuf[c * 32 + ((qi0 + 3 + c) & 31)];
        *(float4*)(ob + (size_t)c * HW + pos) = g;
      }
    }
  }
}

extern "C" void kernel_launch(void* const* d_in, const int* in_sizes, int n_in,
                              void* d_out, int out_size, void* d_ws, size_t ws_size,
                              hipStream_t stream) {
  const float* f0 = (const float*)d_in[0];
  const float* p0 = (const float*)d_in[1];
  const float* f1 = (const float*)d_in[2];
  const float* p1 = (const float*)d_in[3];
  const float* f2 = (const float*)d_in[4];
  const float* p2 = (const float*)d_in[5];
  const float* f3 = (const float*)d_in[6];
  const float* p3 = (const float*)d_in[7];
  const float* text_feats = (const float*)d_in[8];
  const float* amr_feats  = (const float*)d_in[9];
  const int*   text_pad   = (const int*)d_in[10];
  const int*   amr_pad    = (const int*)d_in[11];
  const float* in_w  = (const float*)d_in[12];
  const float* in_b  = (const float*)d_in[13];
  const float* out_w = (const float*)d_in[14];
  const float* out_b = (const float*)d_in[15];
  float* out = (float*)d_out;

  float* ws = (float*)d_ws;
  float* Kws = ws;                                   // 35840 floats
  float* Vws = ws + 35840;                           // 35840 floats
  unsigned short* wq_pack = (unsigned short*)(ws + 71680);  // 65536 ushort
  unsigned short* wo_pack = (unsigned short*)(ws + 71680 + 32768);
  int* vidx = (int*)(ws + 71680 + 65536);            // 160 ints

  prep_kv<<<2 * LM, 256, 0, stream>>>(text_feats, amr_feats, text_pad,
                                      in_w, in_b, Kws, Vws);
  prep_pack<<<64, 256, 0, stream>>>(in_w, out_w, wq_pack, wo_pack,
                                    text_pad, amr_pad, vidx);
  attn_main<<<BT * 267, 256, 0, stream>>>(f0, p0, f1, p1, f2, p2, f3, p3,
                                          Kws, Vws, wq_pack, wo_pack,
                                          in_b, out_b, vidx, out);
}